// Round 3
// baseline (616.024 us; speedup 1.0000x reference)
//
#include <hip/hip_runtime.h>

typedef unsigned short ushort_t;
typedef __attribute__((ext_vector_type(8))) short short8;
typedef __attribute__((ext_vector_type(4))) float floatx4;
typedef __attribute__((ext_vector_type(4))) unsigned int uint4v;

static __device__ __forceinline__ unsigned short f2bf_rn(float f) {
  return (unsigned short)((__float_as_uint(f) + 0x8000u) >> 16);  // round-half-up
}
static __device__ __forceinline__ unsigned int packbf(float a, float b) {
  // low ushort = bf16(a), high ushort = bf16(b)
  return ((__float_as_uint(a) + 0x8000u) >> 16) |
         ((__float_as_uint(b) + 0x8000u) & 0xFFFF0000u);
}

// ---------------------------------------------------------------------------
// k1: transpose+cvt expert_w f32 [E=4][D=4096][O=256] -> WT bf16 [E][O][D]
// ---------------------------------------------------------------------------
__global__ __launch_bounds__(256) void k_transpose(const float* __restrict__ We,
                                                   ushort_t* __restrict__ WT) {
  __shared__ float tile[32][33];
  int t = threadIdx.x, tx = t & 31, ty = t >> 5;  // tx 0..31, ty 0..7
  int d0 = blockIdx.x * 32, o0 = blockIdx.y * 32, e = blockIdx.z;
  const float* src = We + (size_t)e * 4096 * 256;
  ushort_t* dst = WT + (size_t)e * 256 * 4096;
#pragma unroll
  for (int r = 0; r < 4; ++r)
    tile[ty + r * 8][tx] = src[(size_t)(d0 + ty + r * 8) * 256 + (o0 + tx)];
  __syncthreads();
#pragma unroll
  for (int r = 0; r < 4; ++r)
    dst[(size_t)(o0 + ty + r * 8) * 4096 + (d0 + tx)] = f2bf_rn(tile[tx][ty + r * 8]);
}

// ---------------------------------------------------------------------------
// k2: routing (all f32). One wave per token. logits = V[b,:] @ Wr, softmax,
// top-2 renormalized. rw_out = routing_weights (output #2, f32),
// gates[b][e] = renormalized gate or 0 (f32, ws).
// ---------------------------------------------------------------------------
__global__ __launch_bounds__(256) void k_routing(const float* __restrict__ V,
                                                 const float* __restrict__ Wr,
                                                 float* __restrict__ rw_out,
                                                 float* __restrict__ gates) {
  int w = threadIdx.x >> 6, lane = threadIdx.x & 63;
  int b = blockIdx.x * 4 + w;
  const float* vrow = V + (size_t)b * 4096;
  float a0 = 0.f, a1 = 0.f, a2 = 0.f, a3 = 0.f;
#pragma unroll
  for (int j = 0; j < 16; ++j) {
    int d = j * 256 + lane * 4;
    float4 vv = *(const float4*)(vrow + d);
    float vals[4] = {vv.x, vv.y, vv.z, vv.w};
#pragma unroll
    for (int u = 0; u < 4; ++u) {
      float4 ww = *(const float4*)(Wr + (size_t)(d + u) * 4);  // 64KB, cache-hot
      a0 += vals[u] * ww.x;
      a1 += vals[u] * ww.y;
      a2 += vals[u] * ww.z;
      a3 += vals[u] * ww.w;
    }
  }
#pragma unroll
  for (int mask = 1; mask < 64; mask <<= 1) {
    a0 += __shfl_xor(a0, mask, 64);
    a1 += __shfl_xor(a1, mask, 64);
    a2 += __shfl_xor(a2, mask, 64);
    a3 += __shfl_xor(a3, mask, 64);
  }
  float mx = fmaxf(fmaxf(a0, a1), fmaxf(a2, a3));
  float e0 = expf(a0 - mx), e1 = expf(a1 - mx), e2 = expf(a2 - mx), e3 = expf(a3 - mx);
  float s = e0 + e1 + e2 + e3;
  float p[4] = {e0 / s, e1 / s, e2 / s, e3 / s};
  int i1 = 0;
#pragma unroll
  for (int k = 1; k < 4; ++k)
    if (p[k] > p[i1]) i1 = k;  // strict > keeps first index on tie (lax.top_k)
  int i2 = (i1 == 0) ? 1 : 0;
#pragma unroll
  for (int k = 0; k < 4; ++k)
    if (k != i1 && p[k] > p[i2]) i2 = k;
  float gs = p[i1] + p[i2];
  if (lane < 4) {
    rw_out[(size_t)b * 4 + lane] = p[lane];
    float g = (lane == i1 || lane == i2) ? (p[lane] / gs) : 0.f;
    gates[(size_t)b * 4 + lane] = g;
  }
}

// ---------------------------------------------------------------------------
// k3: fused all-expert GEMM + gated combine, f32 in / f32 out, bf16 MFMA.
// kt-outer, e-inner with 4 accumulator sets: V tile staged ONCE per K-step
// (f32 -> bf16 cvt in staging), B tiles for all 4 experts staged per K-step.
// Block tile 128(m) x 64(n), BK=64. Grid (4, 128) = 512 blocks, 256 thr.
// LDS: A 16KB + B 4x8KB = 48KB. XOR-swizzled 16B chunks, conflict-free.
// ---------------------------------------------------------------------------
#define BM 128
#define BN 64
#define BK 64

__global__ __launch_bounds__(256, 2) void k_gemm_moe(const float* __restrict__ V,
                                                     const ushort_t* __restrict__ WT,
                                                     const float* __restrict__ gates,
                                                     float* __restrict__ out) {
  const int Kd = 4096;
  int bn = blockIdx.x;  // 0..3   n0 over O=256
  int bm = blockIdx.y;  // 0..127 m0 over B=16384
  int m0 = bm * BM, n0 = bn * BN;

  __shared__ __align__(16) ushort_t Asm[BM * BK];      // 16 KB bf16
  __shared__ __align__(16) ushort_t Bsm[4 * BN * BK];  // 32 KB bf16 (per-expert 4K ushorts)

  int t = threadIdx.x;
  int w = t >> 6, lane = t & 63;
  int quad = lane >> 4, mi = lane & 15;
  int wm = (w >> 1) * 64, wn = (w & 1) * 32;  // wave sub-tile 64x32

  // ---- staging maps ----
  // A: 1024 16B-chunks (row=0..127, c=0..7); 4 per thread. Source f32.
  int aG[4], aL[4];
#pragma unroll
  for (int j = 0; j < 4; ++j) {
    int q = j * 256 + t;
    int row = q >> 3, c = q & 7;
    aG[j] = (m0 + row) * Kd + c * 8;                 // float index (+k0 at use)
    aL[j] = (row * 8 + (c ^ (row & 7))) * 8;         // ushort offset
  }
  // B: 4 experts x 512 chunks = 2048; 8 per thread. Source bf16.
  int bG[8], bL[8];
#pragma unroll
  for (int j = 0; j < 8; ++j) {
    int q = j * 256 + t;
    int eb = q >> 9, rc = q & 511;
    int r = rc >> 3, c = rc & 7;
    bG[j] = eb * (256 * Kd) + (n0 + r) * Kd + c * 8;  // ushort index (+k0 at use)
    bL[j] = eb * (BN * BK) + (r * 8 + (c ^ (r & 7))) * 8;
  }

  // ---- fragment read offsets (ushort units, pre-swizzled) ----
  int aOff[2][4], bOff[2][2];
#pragma unroll
  for (int k32 = 0; k32 < 2; ++k32) {
    int cc = k32 * 4 + quad;
#pragma unroll
    for (int i = 0; i < 4; ++i) {
      int rowa = wm + i * 16 + mi;
      aOff[k32][i] = (rowa * 8 + (cc ^ (rowa & 7))) * 8;
    }
#pragma unroll
    for (int j = 0; j < 2; ++j) {
      int rowb = wn + j * 16 + mi;
      bOff[k32][j] = (rowb * 8 + (cc ^ (rowb & 7))) * 8;
    }
  }

  floatx4 zero = {0.f, 0.f, 0.f, 0.f};
  floatx4 acc[4][4][2];  // [expert][i][j]
#pragma unroll
  for (int e = 0; e < 4; ++e)
#pragma unroll
    for (int i = 0; i < 4; ++i)
#pragma unroll
      for (int j = 0; j < 2; ++j) acc[e][i][j] = zero;

  for (int kt = 0; kt < Kd / BK; ++kt) {
    int k0 = kt * BK;
    // stage A (f32 -> bf16)
#pragma unroll
    for (int j = 0; j < 4; ++j) {
      const float* ap = V + (size_t)(aG[j] + k0);
      float4 x = *(const float4*)ap;
      float4 y = *(const float4*)(ap + 4);
      uint4v uv;
      uv.x = packbf(x.x, x.y);
      uv.y = packbf(x.z, x.w);
      uv.z = packbf(y.x, y.y);
      uv.w = packbf(y.z, y.w);
      *(uint4v*)(Asm + aL[j]) = uv;
    }
    // stage B (bf16 passthrough), all 4 experts
#pragma unroll
    for (int j = 0; j < 8; ++j)
      *(short8*)(Bsm + bL[j]) = *(const short8*)(WT + (size_t)(bG[j] + k0));
    __syncthreads();
#pragma unroll
    for (int k32 = 0; k32 < 2; ++k32) {
      short8 af[4];
#pragma unroll
      for (int i = 0; i < 4; ++i) af[i] = *(const short8*)(Asm + aOff[k32][i]);
#pragma unroll
      for (int e = 0; e < 4; ++e) {
        short8 bfr[2];
#pragma unroll
        for (int j = 0; j < 2; ++j)
          bfr[j] = *(const short8*)(Bsm + e * (BN * BK) + bOff[k32][j]);
#pragma unroll
        for (int i = 0; i < 4; ++i)
#pragma unroll
          for (int j = 0; j < 2; ++j)
            acc[e][i][j] =
                __builtin_amdgcn_mfma_f32_16x16x32_bf16(af[i], bfr[j], acc[e][i][j], 0, 0, 0);
      }
    }
    __syncthreads();
  }

  // ---- epilogue: gated combine across experts, single f32 store ----
  // C/D layout: col = lane&15 (n), row = quad*4 + reg (m)
#pragma unroll
  for (int i = 0; i < 4; ++i) {
#pragma unroll
    for (int r = 0; r < 4; ++r) {
      int m = m0 + wm + i * 16 + quad * 4 + r;
      float4 gv = *(const float4*)(gates + (size_t)m * 4);
#pragma unroll
      for (int j = 0; j < 2; ++j) {
        float sv = gv.x * acc[0][i][j][r] + gv.y * acc[1][i][j][r] +
                   gv.z * acc[2][i][j][r] + gv.w * acc[3][i][j][r];
        out[(size_t)m * 256 + n0 + wn + j * 16 + mi] = sv;
      }
    }
  }
}

// ---------------------------------------------------------------------------
extern "C" void kernel_launch(void* const* d_in, const int* in_sizes, int n_in,
                              void* d_out, int out_size, void* d_ws, size_t ws_size,
                              hipStream_t stream) {
  const float* V = (const float*)d_in[0];   // [16384][4096] f32
  const float* Wr = (const float*)d_in[1];  // [4096][4] f32
  const float* We = (const float*)d_in[2];  // [4][4096][256] f32

  float* out_moe = (float*)d_out;                   // [16384][256] f32
  float* out_rw = out_moe + (size_t)16384 * 256;    // [16384][4] f32

  char* ws = (char*)d_ws;
  float* gates = (float*)ws;                 // 256 KB [16384][4] f32
  ushort_t* WT = (ushort_t*)(ws + 262144);   // 8 MB   [4][256][4096] bf16
                                             // total ws use: 8.25 MB

  k_transpose<<<dim3(128, 8, 4), 256, 0, stream>>>(We, WT);
  k_routing<<<dim3(4096), 256, 0, stream>>>(V, Wr, out_rw, gates);
  k_gemm_moe<<<dim3(4, 128), 256, 0, stream>>>(V, WT, gates, out_moe);
}

// Round 4
// 597.958 us; speedup vs baseline: 1.0302x; 1.0302x over previous
//
#include <hip/hip_runtime.h>

typedef unsigned short ushort_t;
typedef __attribute__((ext_vector_type(8))) short short8;
typedef __attribute__((ext_vector_type(4))) float floatx4;
typedef __attribute__((ext_vector_type(4))) unsigned int uint4v;

static __device__ __forceinline__ unsigned short f2bf_rn(float f) {
  return (unsigned short)((__float_as_uint(f) + 0x8000u) >> 16);
}
static __device__ __forceinline__ unsigned int packbf(float a, float b) {
  return ((__float_as_uint(a) + 0x8000u) >> 16) |
         ((__float_as_uint(b) + 0x8000u) & 0xFFFF0000u);
}

// ---------------------------------------------------------------------------
// k1: transpose+cvt expert_w f32 [E=4][D=4096][O=256] -> WT bf16 [E][O][D]
// ---------------------------------------------------------------------------
__global__ __launch_bounds__(256) void k_transpose(const float* __restrict__ We,
                                                   ushort_t* __restrict__ WT) {
  __shared__ float tile[32][33];
  int t = threadIdx.x, tx = t & 31, ty = t >> 5;
  int d0 = blockIdx.x * 32, o0 = blockIdx.y * 32, e = blockIdx.z;
  const float* src = We + (size_t)e * 4096 * 256;
  ushort_t* dst = WT + (size_t)e * 256 * 4096;
#pragma unroll
  for (int r = 0; r < 4; ++r)
    tile[ty + r * 8][tx] = src[(size_t)(d0 + ty + r * 8) * 256 + (o0 + tx)];
  __syncthreads();
#pragma unroll
  for (int r = 0; r < 4; ++r)
    dst[(size_t)(o0 + ty + r * 8) * 4096 + (d0 + tx)] = f2bf_rn(tile[tx][ty + r * 8]);
}

// ---------------------------------------------------------------------------
// k1b: router weight transpose f32 [4096][4] -> WrT32 [4][4096] f32
// ---------------------------------------------------------------------------
__global__ __launch_bounds__(256) void k_prep_router(const float* __restrict__ Wr,
                                                     float* __restrict__ WrT32) {
  int d = blockIdx.x * 256 + threadIdx.x;  // 16 blocks
  float4 w = *(const float4*)(Wr + (size_t)d * 4);
  WrT32[d] = w.x;
  WrT32[4096 + d] = w.y;
  WrT32[2 * 4096 + d] = w.z;
  WrT32[3 * 4096 + d] = w.w;
}

// ---------------------------------------------------------------------------
// k2: routing, all-f32 (exact top-2 selection). One wave per token.
// All loads coalesced: V float4 1KB/instr; WrT32 rows float4, 64KB L2-hot.
// ---------------------------------------------------------------------------
__global__ __launch_bounds__(256) void k_routing(const float* __restrict__ V,
                                                 const float* __restrict__ WrT32,
                                                 float* __restrict__ rw_out,
                                                 float* __restrict__ gates) {
  int w = threadIdx.x >> 6, lane = threadIdx.x & 63;
  int b = blockIdx.x * 4 + w;
  const float* vrow = V + (size_t)b * 4096;
  float a0 = 0.f, a1 = 0.f, a2 = 0.f, a3 = 0.f;
#pragma unroll
  for (int j = 0; j < 16; ++j) {
    int d = j * 256 + lane * 4;
    float4 vv = *(const float4*)(vrow + d);
    float4 w0 = *(const float4*)(WrT32 + d);
    float4 w1 = *(const float4*)(WrT32 + 4096 + d);
    float4 w2 = *(const float4*)(WrT32 + 2 * 4096 + d);
    float4 w3 = *(const float4*)(WrT32 + 3 * 4096 + d);
    a0 += vv.x * w0.x + vv.y * w0.y + vv.z * w0.z + vv.w * w0.w;
    a1 += vv.x * w1.x + vv.y * w1.y + vv.z * w1.z + vv.w * w1.w;
    a2 += vv.x * w2.x + vv.y * w2.y + vv.z * w2.z + vv.w * w2.w;
    a3 += vv.x * w3.x + vv.y * w3.y + vv.z * w3.z + vv.w * w3.w;
  }
#pragma unroll
  for (int mask = 1; mask < 64; mask <<= 1) {
    a0 += __shfl_xor(a0, mask, 64);
    a1 += __shfl_xor(a1, mask, 64);
    a2 += __shfl_xor(a2, mask, 64);
    a3 += __shfl_xor(a3, mask, 64);
  }
  float mx = fmaxf(fmaxf(a0, a1), fmaxf(a2, a3));
  float e0 = expf(a0 - mx), e1 = expf(a1 - mx), e2 = expf(a2 - mx), e3 = expf(a3 - mx);
  float s = e0 + e1 + e2 + e3;
  float p[4] = {e0 / s, e1 / s, e2 / s, e3 / s};
  int i1 = 0;
#pragma unroll
  for (int k = 1; k < 4; ++k)
    if (p[k] > p[i1]) i1 = k;  // strict >: first index wins ties (lax.top_k)
  int i2 = (i1 == 0) ? 1 : 0;
#pragma unroll
  for (int k = 0; k < 4; ++k)
    if (k != i1 && p[k] > p[i2]) i2 = k;
  float gs = p[i1] + p[i2];
  if (lane < 4) {
    rw_out[(size_t)b * 4 + lane] = p[lane];
    gates[(size_t)b * 4 + lane] = (lane == i1 || lane == i2) ? (p[lane] / gs) : 0.f;
  }
}

// ---------------------------------------------------------------------------
// k3: fused all-expert GEMM + gated combine, software-pipelined K-loop.
// Block tile 128(m) x 64(n), BK=64, e-inner with 4 acc sets; V staged once.
// Pipeline: stores(kt) -> sync -> issue loads(kt+1) -> mfma(kt) -> sync.
// Loads overlap the MFMA section instead of sitting between barriers.
// ---------------------------------------------------------------------------
#define BM 128
#define BN 64
#define BK 64

__global__ __launch_bounds__(256, 2) void k_gemm_moe(const float* __restrict__ V,
                                                     const ushort_t* __restrict__ WT,
                                                     const float* __restrict__ gates,
                                                     float* __restrict__ out) {
  const int Kd = 4096;
  int bn = blockIdx.x;  // 0..3
  int bm = blockIdx.y;  // 0..127
  int m0 = bm * BM, n0 = bn * BN;

  __shared__ __align__(16) ushort_t Asm[BM * BK];      // 16 KB bf16
  __shared__ __align__(16) ushort_t Bsm[4 * BN * BK];  // 32 KB bf16

  int t = threadIdx.x;
  int w = t >> 6, lane = t & 63;
  int quad = lane >> 4, mi = lane & 15;
  int wm = (w >> 1) * 64, wn = (w & 1) * 32;

  // A: 1024 bf16 16B-chunks, 4/thread (each <- 32B of f32)
  int aG[4], aL[4];
#pragma unroll
  for (int j = 0; j < 4; ++j) {
    int q = j * 256 + t;
    int row = q >> 3, c = q & 7;
    aG[j] = (m0 + row) * Kd + c * 8;
    aL[j] = (row * 8 + (c ^ (row & 7))) * 8;
  }
  // B: 4 experts x 512 chunks, 8/thread
  int bG[8], bL[8];
#pragma unroll
  for (int j = 0; j < 8; ++j) {
    int q = j * 256 + t;
    int eb = q >> 9, rc = q & 511;
    int r = rc >> 3, c = rc & 7;
    bG[j] = eb * (256 * Kd) + (n0 + r) * Kd + c * 8;
    bL[j] = eb * (BN * BK) + (r * 8 + (c ^ (r & 7))) * 8;
  }

  int aOff[2][4], bOff[2][2];
#pragma unroll
  for (int k32 = 0; k32 < 2; ++k32) {
    int cc = k32 * 4 + quad;
#pragma unroll
    for (int i = 0; i < 4; ++i) {
      int rowa = wm + i * 16 + mi;
      aOff[k32][i] = (rowa * 8 + (cc ^ (rowa & 7))) * 8;
    }
#pragma unroll
    for (int j = 0; j < 2; ++j) {
      int rowb = wn + j * 16 + mi;
      bOff[k32][j] = (rowb * 8 + (cc ^ (rowb & 7))) * 8;
    }
  }

  floatx4 zero = {0.f, 0.f, 0.f, 0.f};
  floatx4 acc[4][4][2];
#pragma unroll
  for (int e = 0; e < 4; ++e)
#pragma unroll
    for (int i = 0; i < 4; ++i)
#pragma unroll
      for (int j = 0; j < 2; ++j) acc[e][i][j] = zero;

  // ---- prologue: load tile kt=0 into regs ----
  float4 ax[4], ay[4];
  short8 bv[8];
#pragma unroll
  for (int j = 0; j < 4; ++j) {
    const float* ap = V + (size_t)aG[j];
    ax[j] = *(const float4*)ap;
    ay[j] = *(const float4*)(ap + 4);
  }
#pragma unroll
  for (int j = 0; j < 8; ++j) bv[j] = *(const short8*)(WT + (size_t)bG[j]);

  for (int kt = 0; kt < Kd / BK; ++kt) {
    // ---- stores: regs (tile kt) -> LDS ----
#pragma unroll
    for (int j = 0; j < 4; ++j) {
      uint4v uv;
      uv.x = packbf(ax[j].x, ax[j].y);
      uv.y = packbf(ax[j].z, ax[j].w);
      uv.z = packbf(ay[j].x, ay[j].y);
      uv.w = packbf(ay[j].z, ay[j].w);
      *(uint4v*)(Asm + aL[j]) = uv;
    }
#pragma unroll
    for (int j = 0; j < 8; ++j) *(short8*)(Bsm + bL[j]) = bv[j];
    __syncthreads();

    // ---- prefetch tile kt+1 (overlaps the MFMA section below) ----
    if (kt + 1 < Kd / BK) {
      int k0n = (kt + 1) * BK;
#pragma unroll
      for (int j = 0; j < 4; ++j) {
        const float* ap = V + (size_t)(aG[j] + k0n);
        ax[j] = *(const float4*)ap;
        ay[j] = *(const float4*)(ap + 4);
      }
#pragma unroll
      for (int j = 0; j < 8; ++j) bv[j] = *(const short8*)(WT + (size_t)(bG[j] + k0n));
    }

    // ---- MFMA on tile kt ----
#pragma unroll
    for (int k32 = 0; k32 < 2; ++k32) {
      short8 af[4];
#pragma unroll
      for (int i = 0; i < 4; ++i) af[i] = *(const short8*)(Asm + aOff[k32][i]);
#pragma unroll
      for (int e = 0; e < 4; ++e) {
        short8 bfr[2];
#pragma unroll
        for (int j = 0; j < 2; ++j)
          bfr[j] = *(const short8*)(Bsm + e * (BN * BK) + bOff[k32][j]);
#pragma unroll
        for (int i = 0; i < 4; ++i)
#pragma unroll
          for (int j = 0; j < 2; ++j)
            acc[e][i][j] =
                __builtin_amdgcn_mfma_f32_16x16x32_bf16(af[i], bfr[j], acc[e][i][j], 0, 0, 0);
      }
    }
    __syncthreads();
  }

  // ---- epilogue: gated combine, single f32 store ----
#pragma unroll
  for (int i = 0; i < 4; ++i) {
#pragma unroll
    for (int r = 0; r < 4; ++r) {
      int m = m0 + wm + i * 16 + quad * 4 + r;
      float4 gv = *(const float4*)(gates + (size_t)m * 4);
#pragma unroll
      for (int j = 0; j < 2; ++j) {
        float sv = gv.x * acc[0][i][j][r] + gv.y * acc[1][i][j][r] +
                   gv.z * acc[2][i][j][r] + gv.w * acc[3][i][j][r];
        out[(size_t)m * 256 + n0 + wn + j * 16 + mi] = sv;
      }
    }
  }
}

// ---------------------------------------------------------------------------
extern "C" void kernel_launch(void* const* d_in, const int* in_sizes, int n_in,
                              void* d_out, int out_size, void* d_ws, size_t ws_size,
                              hipStream_t stream) {
  const float* V = (const float*)d_in[0];   // [16384][4096] f32
  const float* Wr = (const float*)d_in[1];  // [4096][4] f32
  const float* We = (const float*)d_in[2];  // [4][4096][256] f32

  float* out_moe = (float*)d_out;                 // [16384][256] f32
  float* out_rw = out_moe + (size_t)16384 * 256;  // [16384][4] f32

  char* ws = (char*)d_ws;
  float* gates = (float*)ws;                       // 256 KB
  ushort_t* WT = (ushort_t*)(ws + 262144);         // 8 MB bf16 [4][256][4096]
  float* WrT32 = (float*)(ws + 262144 + 8388608);  // 64 KB f32 [4][4096]

  k_transpose<<<dim3(128, 8, 4), 256, 0, stream>>>(We, WT);
  k_prep_router<<<dim3(16), 256, 0, stream>>>(Wr, WrT32);
  k_routing<<<dim3(4096), 256, 0, stream>>>(V, WrT32, out_rw, gates);
  k_gemm_moe<<<dim3(4, 128), 256, 0, stream>>>(V, WT, gates, out_moe);
}